// Round 2
// baseline (107.411 us; speedup 1.0000x reference)
//
#include <hip/hip_runtime.h>
#include <hip/hip_bf16.h>

#define LSEQ 2048
#define BB   2048
#define TT   7
#define REC  52   // 49 matrix + scale + score + maskcnt (float), 208 B = 16B-aligned

// ---------------------------------------------------------------------------
// Kernel 1: per-(batch, chunk) composite transition operator in exp-space.
// M starts as identity; per step i: M[s][t] = (sum_r M[s][r]*expE[r][t]) * exp(em[i][t])
// expE selected per-lane by contagion flag (qmask[i] != qmask[i-1]).
// Also accumulates the gold-path partial score and the mask count.
// ---------------------------------------------------------------------------
template<int K>
__global__ __launch_bounds__(256)
void crf_chunk_kernel(const float* __restrict__ em,
                      const int*   __restrict__ tags,
                      const int*   __restrict__ qmask,
                      const int*   __restrict__ mask,
                      const float* __restrict__ self_t,
                      const float* __restrict__ other_t,
                      float* __restrict__ recs) {
  constexpr int C = LSEQ / K;
  __shared__ __align__(16) float sE[2][REC];   // exp(transitions): [0]=self, [1]=other
  __shared__ __align__(16) float sT[2][REC];   // raw transitions (for gold-path score)
  int tid = threadIdx.x;
  if (tid < 49) {
    float sv = self_t[tid];
    float ov = other_t[tid];
    sE[0][tid] = expf(sv);
    sE[1][tid] = expf(ov);
    sT[0][tid] = sv;
    sT[1][tid] = ov;
  } else if (tid < REC) {
    sE[0][tid] = 0.f; sE[1][tid] = 0.f;
    sT[0][tid] = 0.f; sT[1][tid] = 0.f;
  }
  __syncthreads();

  int gid = blockIdx.x * blockDim.x + tid;
  int b = gid & (BB - 1);
  int c = gid >> 11;            // gid / BB

  float M[TT][TT];
#pragma unroll
  for (int s = 0; s < TT; ++s)
#pragma unroll
    for (int t = 0; t < TT; ++t) M[s][t] = (s == t) ? 1.0f : 0.0f;

  float sc = 0.0f;
  int   mc = 0;
  int i     = c * C;
  int i_end = i + C;
  int tp, qp;
  if (c == 0) {
    mc = mask[b];               // include i=0 in the mask count
    tp = tags[b];
    qp = qmask[b];
    i  = 1;                     // step 0 is the alpha-init, handled in combine
  } else {
    tp = tags[(size_t)(i - 1) * BB + b];
    qp = qmask[(size_t)(i - 1) * BB + b];
  }

  float Er[REC];
  int contPrev = -1;            // force initial load

  for (; i < i_end; ++i) {
    size_t base = (size_t)i * BB + b;
    const float* eb = em + base * TT;
    float e0 = eb[0], e1 = eb[1], e2 = eb[2], e3 = eb[3],
          e4 = eb[4], e5 = eb[5], e6 = eb[6];
    int tg = tags[base];
    int qm = qmask[base];
    int mi = mask[base];
    int cont = (qm != qp) ? 1 : 0;

    // Reload exp(trans) into registers only when any lane's contagion flips.
    if (__any(cont != contPrev)) {
      const float4* p = reinterpret_cast<const float4*>(sE[cont]);
#pragma unroll
      for (int k2 = 0; k2 < 13; ++k2) {
        float4 v = p[k2];
        Er[4*k2+0] = v.x; Er[4*k2+1] = v.y; Er[4*k2+2] = v.z; Er[4*k2+3] = v.w;
      }
      contPrev = cont;
    }

    float ee0 = expf(e0), ee1 = expf(e1), ee2 = expf(e2), ee3 = expf(e3),
          ee4 = expf(e4), ee5 = expf(e5), ee6 = expf(e6);

    // gold-path partial score
    float etag = eb[tg];                       // runtime-indexed global load (L1 hit)
    float ttag = sT[cont][tp * TT + tg];       // per-lane LDS read
    if (mi) { sc += ttag + etag; ++mc; }

    // M <- M x (expE col-scaled by ee); each row depends only on its own old row.
    if (!__any(mi == 0)) {
#pragma unroll
      for (int s = 0; s < TT; ++s) {
        float t0 = 0.f, t1 = 0.f, t2 = 0.f, t3 = 0.f, t4 = 0.f, t5 = 0.f, t6 = 0.f;
#pragma unroll
        for (int r = 0; r < TT; ++r) {
          float ms = M[s][r];
          t0 = fmaf(ms, Er[r*TT+0], t0);
          t1 = fmaf(ms, Er[r*TT+1], t1);
          t2 = fmaf(ms, Er[r*TT+2], t2);
          t3 = fmaf(ms, Er[r*TT+3], t3);
          t4 = fmaf(ms, Er[r*TT+4], t4);
          t5 = fmaf(ms, Er[r*TT+5], t5);
          t6 = fmaf(ms, Er[r*TT+6], t6);
        }
        M[s][0] = t0 * ee0; M[s][1] = t1 * ee1; M[s][2] = t2 * ee2;
        M[s][3] = t3 * ee3; M[s][4] = t4 * ee4; M[s][5] = t5 * ee5;
        M[s][6] = t6 * ee6;
      }
    } else {
#pragma unroll
      for (int s = 0; s < TT; ++s) {
        float t0 = 0.f, t1 = 0.f, t2 = 0.f, t3 = 0.f, t4 = 0.f, t5 = 0.f, t6 = 0.f;
#pragma unroll
        for (int r = 0; r < TT; ++r) {
          float ms = M[s][r];
          t0 = fmaf(ms, Er[r*TT+0], t0);
          t1 = fmaf(ms, Er[r*TT+1], t1);
          t2 = fmaf(ms, Er[r*TT+2], t2);
          t3 = fmaf(ms, Er[r*TT+3], t3);
          t4 = fmaf(ms, Er[r*TT+4], t4);
          t5 = fmaf(ms, Er[r*TT+5], t5);
          t6 = fmaf(ms, Er[r*TT+6], t6);
        }
        M[s][0] = mi ? t0 * ee0 : M[s][0];
        M[s][1] = mi ? t1 * ee1 : M[s][1];
        M[s][2] = mi ? t2 * ee2 : M[s][2];
        M[s][3] = mi ? t3 * ee3 : M[s][3];
        M[s][4] = mi ? t4 * ee4 : M[s][4];
        M[s][5] = mi ? t5 * ee5 : M[s][5];
        M[s][6] = mi ? t6 * ee6 : M[s][6];
      }
    }
    tp = tg; qp = qm;
  }

  // renormalize and write record
  float mx = M[0][0];
#pragma unroll
  for (int s = 0; s < TT; ++s)
#pragma unroll
    for (int t = 0; t < TT; ++t) mx = fmaxf(mx, M[s][t]);
  float inv = 1.0f / mx;

  float outv[REC];
#pragma unroll
  for (int s = 0; s < TT; ++s)
#pragma unroll
    for (int t = 0; t < TT; ++t) outv[s*TT+t] = M[s][t] * inv;
  outv[49] = logf(mx);
  outv[50] = sc;
  outv[51] = (float)mc;

  float4* rp = reinterpret_cast<float4*>(recs + ((size_t)c * BB + b) * REC);
#pragma unroll
  for (int k2 = 0; k2 < 13; ++k2)
    rp[k2] = make_float4(outv[4*k2+0], outv[4*k2+1], outv[4*k2+2], outv[4*k2+3]);
}

// ---------------------------------------------------------------------------
// Kernel 2: one wave per batch; sequentially fold the K chunk operators into
// the alpha vector (exp-space, renormalized each step), then finish score/logZ.
// ---------------------------------------------------------------------------
__global__ __launch_bounds__(64)
void crf_combine_kernel(const float* __restrict__ recs,
                        const float* __restrict__ em,
                        const int*   __restrict__ tags,
                        const float* __restrict__ start_t,
                        const float* __restrict__ end_t,
                        float* __restrict__ results,
                        int K) {
  int b = blockIdx.x;
  int j = threadIdx.x;
  __shared__ float lds[REC];

  float al[TT];
#pragma unroll
  for (int t = 0; t < TT; ++t) al[t] = expf(start_t[t] + em[(size_t)b * TT + t]);

  float lacc = 0.f, sc = 0.f, mcf = 0.f;
  float r = (j < REC) ? recs[(size_t)b * REC + j] : 0.f;   // record (c=0, b)

  for (int c = 0; c < K; ++c) {
    if (j < REC) lds[j] = r;
    __syncthreads();
    if (c + 1 < K && j < REC)
      r = recs[((size_t)(c + 1) * BB + b) * REC + j];      // prefetch next

    float nt = 0.f;
    if (j < TT) {
#pragma unroll
      for (int s = 0; s < TT; ++s) nt = fmaf(al[s], lds[s * TT + j], nt);
    }
    float lc  = lds[49];
    float scc = lds[50];
    float mcc = lds[51];
    __syncthreads();

    float na[TT];
#pragma unroll
    for (int t = 0; t < TT; ++t) na[t] = __shfl(nt, t);
    float mx = na[0];
#pragma unroll
    for (int t = 1; t < TT; ++t) mx = fmaxf(mx, na[t]);
    float inv = 1.0f / mx;
#pragma unroll
    for (int t = 0; t < TT; ++t) al[t] = na[t] * inv;
    lacc += logf(mx) + lc;
    sc += scc; mcf += mcc;
  }

  if (j == 0) {
    float z = 0.f;
#pragma unroll
    for (int t = 0; t < TT; ++t) z += al[t] * expf(end_t[t]);
    float logZ = lacc + logf(z);
    int t0 = tags[b];
    float s0 = start_t[t0] + em[(size_t)b * TT + t0];
    int se = (int)mcf - 1;
    int te = tags[(size_t)se * BB + b];
    results[b] = (sc + s0 + end_t[te]) - logZ;
  }
}

// ---------------------------------------------------------------------------
// Kernel 3: deterministic tree-reduce of the 2048 per-batch results.
// ---------------------------------------------------------------------------
__global__ __launch_bounds__(256)
void crf_reduce_kernel(const float* __restrict__ results, float* __restrict__ out) {
  __shared__ float s[256];
  int t = threadIdx.x;
  float v = 0.f;
  for (int i = t; i < BB; i += 256) v += results[i];
  s[t] = v;
  __syncthreads();
  for (int off = 128; off > 0; off >>= 1) {
    if (t < off) s[t] += s[t + off];
    __syncthreads();
  }
  if (t == 0) out[0] = s[0];
}

extern "C" void kernel_launch(void* const* d_in, const int* in_sizes, int n_in,
                              void* d_out, int out_size, void* d_ws, size_t ws_size,
                              hipStream_t stream) {
  const float* em      = (const float*)d_in[0];
  const int*   tags    = (const int*)d_in[1];
  const int*   qmask   = (const int*)d_in[2];
  const int*   mask    = (const int*)d_in[3];
  const float* start_t = (const float*)d_in[4];
  const float* end_t   = (const float*)d_in[5];
  const float* self_t  = (const float*)d_in[6];
  const float* other_t = (const float*)d_in[7];

  float* recs = (float*)d_ws;

  // choose chunk count to fit workspace: K*B*REC*4 + B*4 bytes
  int K = 64;
  auto need = [](int k) { return (size_t)k * BB * REC * 4 + (size_t)BB * 4; };
  if      (ws_size >= need(64)) K = 64;
  else if (ws_size >= need(32)) K = 32;
  else if (ws_size >= need(16)) K = 16;
  else if (ws_size >= need(8))  K = 8;
  else                          K = 4;

  float* results = recs + (size_t)K * BB * REC;

  int threads = 256;
  int blocks = (K * BB) / threads;
  switch (K) {
    case 64: crf_chunk_kernel<64><<<blocks, threads, 0, stream>>>(em, tags, qmask, mask, self_t, other_t, recs); break;
    case 32: crf_chunk_kernel<32><<<blocks, threads, 0, stream>>>(em, tags, qmask, mask, self_t, other_t, recs); break;
    case 16: crf_chunk_kernel<16><<<blocks, threads, 0, stream>>>(em, tags, qmask, mask, self_t, other_t, recs); break;
    case 8:  crf_chunk_kernel<8 ><<<blocks, threads, 0, stream>>>(em, tags, qmask, mask, self_t, other_t, recs); break;
    default: crf_chunk_kernel<4 ><<<blocks, threads, 0, stream>>>(em, tags, qmask, mask, self_t, other_t, recs); break;
  }

  crf_combine_kernel<<<BB, 64, 0, stream>>>(recs, em, tags, start_t, end_t, results, K);
  crf_reduce_kernel<<<1, 256, 0, stream>>>(results, (float*)d_out);
}